// Round 13
// baseline (49.923 us; speedup 1.0000x reference)
//
#include <hip/hip_runtime.h>
#include <math.h>

#define BB 16
#define CC 256
#define HH 64
#define WW 32
#define NN (HH*WW)            // 2048
#define NEGC (-9e15f)
#define CPAD 136              // bf16 elems per LDS row: 272B stride, 16B-aligned rows

typedef __attribute__((ext_vector_type(8))) short bf16x8;
typedef __attribute__((ext_vector_type(4))) float f32x4;

// scratch (capture-safe device globals; fully rewritten before any read each call)
__device__ float g_wlo[BB*CC];            // channel-softmax weight on c-1
__device__ float g_whi[BB*CC];            // channel-softmax weight on c+1
__device__ float g_as[(size_t)BB*NN*64];  // as[b][p][k]: alpha (0..31), sigma (32..63)
__device__ float g_part[BB*32*256];       // per-(b,ptile) pair-dot partials
__device__ float g_w8[(size_t)BB*NN*8];   // spatial softmax weights per position

__device__ __forceinline__ unsigned short f2bf(float f) {   // RNE f32->bf16
    unsigned int u = __float_as_uint(f);
    u += 0x7FFFu + ((u >> 16) & 1u);
    return (unsigned short)(u >> 16);
}

// ============ K1: alpha/sigma GEMM via MFMA bf16 + fp32 pair dots ============
// as[b][p][k] = relu(bias[k] + sum_c (W[k][c]*inv[k]) * x[b][c][p])   (bf16 MFMA)
// g_part[b][ptile][c] = sum over ptile's 64 positions of x*x (fp32, from global regs)
// grid 512 = b(16) x ptile(32).  Two 128-channel halves staged in LDS.
__global__ __launch_bounds__(256) void k_gemm(
        const float* __restrict__ x,
        const float* __restrict__ wa, const float* __restrict__ ga,
        const float* __restrict__ va, const float* __restrict__ ba,
        const float* __restrict__ ma, const float* __restrict__ wsig,
        const float* __restrict__ gs, const float* __restrict__ vs,
        const float* __restrict__ bs, const float* __restrict__ ms) {
    __shared__ unsigned short xbuf[64*CPAD];   // [p][c_local] bf16
    __shared__ unsigned short wbuf[64*CPAD];   // [k][c_local] bf16 (BN-folded)
    int blk = blockIdx.x;
    int b = blk >> 5, tile = blk & 31;
    int t = threadIdx.x;
    int p0 = tile*64;
    const float* xb = x + (size_t)b*CC*NN + p0;

    // W staging row info: thread t stages k = t>>2, 32 c's at sub*32
    int kw = t >> 2, sub = t & 3;
    const float* wrow; float g_, v_;
    if (kw < 32) { g_ = ga[kw]; v_ = va[kw]; wrow = wa + kw*CC; }
    else         { g_ = gs[kw-32]; v_ = vs[kw-32]; wrow = wsig + (kw-32)*CC; }
    float invk = g_ * rsqrtf(v_ + 1e-5f);

    // x staging / pair-dot map: thread = (g = t>>4: 8-c-row group, q = t&15: pos quad)
    int g = t >> 4, q = t & 15;
    int wv_ = t >> 6;                 // wave id: 16 positions per wave
    int lane = t & 63;
    int pcol = lane & 15, grp = lane >> 4;

    f32x4 acc[4];
    #pragma unroll
    for (int i = 0; i < 4; ++i) acc[i] = (f32x4){0.f, 0.f, 0.f, 0.f};

    #pragma unroll
    for (int h = 0; h < 2; ++h) {
        if (h) __syncthreads();       // prior half's MFMA reads complete
        // ---- stage x (bf16 transpose scatter) + fp32 pair partials ----
        float pp[8];
        #pragma unroll
        for (int i = 0; i < 8; ++i) pp[i] = 0.f;
        float4 prev = make_float4(0.f, 0.f, 0.f, 0.f);
        #pragma unroll
        for (int i = 0; i <= 8; ++i) {
            int c = h*128 + g*8 + i;
            float4 v = make_float4(0.f, 0.f, 0.f, 0.f);
            if (c < CC) v = *(const float4*)(xb + (size_t)c*NN + q*4);
            if (i < 8) {
                int cl = g*8 + i;
                xbuf[(q*4+0)*CPAD + cl] = f2bf(v.x);
                xbuf[(q*4+1)*CPAD + cl] = f2bf(v.y);
                xbuf[(q*4+2)*CPAD + cl] = f2bf(v.z);
                xbuf[(q*4+3)*CPAD + cl] = f2bf(v.w);
            }
            if (i > 0) {
                pp[i-1] = fmaf(prev.x, v.x, pp[i-1]);
                pp[i-1] = fmaf(prev.y, v.y, pp[i-1]);
                pp[i-1] = fmaf(prev.z, v.z, pp[i-1]);
                pp[i-1] = fmaf(prev.w, v.w, pp[i-1]);
            }
            prev = v;
        }
        // reduce each pair over the 16 q-lanes (contiguous 16-lane group in-wave)
        float myv = 0.f;
        #pragma unroll
        for (int i = 0; i < 8; ++i) {
            float r = pp[i];
            r += __shfl_xor(r, 1, 64);
            r += __shfl_xor(r, 2, 64);
            r += __shfl_xor(r, 4, 64);
            r += __shfl_xor(r, 8, 64);
            if (q == i) myv = r;
        }
        if (q < 8) {
            int c = h*128 + g*8 + q;          // c==255 -> myv==0 (zero row product)
            g_part[(b*32 + tile)*256 + c] = myv;
        }
        // ---- stage W (BN-folded, bf16) ----
        #pragma unroll
        for (int m = 0; m < 8; ++m) {
            int cl = sub*32 + m*4;
            float4 w4 = *(const float4*)(wrow + h*128 + cl);
            unsigned int pk0 = (unsigned int)f2bf(w4.x*invk) |
                               ((unsigned int)f2bf(w4.y*invk) << 16);
            unsigned int pk1 = (unsigned int)f2bf(w4.z*invk) |
                               ((unsigned int)f2bf(w4.w*invk) << 16);
            *(unsigned int*)&wbuf[kw*CPAD + cl]     = pk0;
            *(unsigned int*)&wbuf[kw*CPAD + cl + 2] = pk1;
        }
        __syncthreads();
        // ---- MFMA: 4 c-steps x 4 k-tiles ----
        #pragma unroll
        for (int cs = 0; cs < 4; ++cs) {
            int c_off = cs*32 + grp*8;
            bf16x8 bfrag = *(const bf16x8*)&xbuf[(wv_*16 + pcol)*CPAD + c_off];
            #pragma unroll
            for (int kt = 0; kt < 4; ++kt) {
                bf16x8 afrag = *(const bf16x8*)&wbuf[(kt*16 + pcol)*CPAD + c_off];
                acc[kt] = __builtin_amdgcn_mfma_f32_16x16x32_bf16(afrag, bfrag, acc[kt], 0, 0, 0);
            }
        }
    }

    // epilogue: D[row=k'=grp*4+reg][col=p'=pcol]; bias recomputed inline
    #pragma unroll
    for (int kt = 0; kt < 4; ++kt) {
        int k0 = kt*16 + grp*4;
        float4 gv, vv, bv, mv;
        if (k0 < 32) {
            gv = *(const float4*)(ga + k0); vv = *(const float4*)(va + k0);
            bv = *(const float4*)(ba + k0); mv = *(const float4*)(ma + k0);
        } else {
            gv = *(const float4*)(gs + k0-32); vv = *(const float4*)(vs + k0-32);
            bv = *(const float4*)(bs + k0-32); mv = *(const float4*)(ms + k0-32);
        }
        float i0 = gv.x * rsqrtf(vv.x + 1e-5f);
        float i1 = gv.y * rsqrtf(vv.y + 1e-5f);
        float i2 = gv.z * rsqrtf(vv.z + 1e-5f);
        float i3 = gv.w * rsqrtf(vv.w + 1e-5f);
        float4 r;
        r.x = fmaxf(acc[kt][0] + (bv.x - mv.x*i0), 0.f);
        r.y = fmaxf(acc[kt][1] + (bv.y - mv.y*i1), 0.f);
        r.z = fmaxf(acc[kt][2] + (bv.z - mv.z*i2), 0.f);
        r.w = fmaxf(acc[kt][3] + (bv.w - mv.w*i3), 0.f);
        *(float4*)(g_as + (((size_t)(b*NN + p0 + wv_*16 + pcol)) << 6) + k0) = r;
    }
}

// ---------------- K2: spatial softmax weights (blocks < WBLK) + channel softmax (rest) ----
#define WBLK (BB*NN/32)   // 1024: each block does 32 positions x 8 neighbors
__global__ __launch_bounds__(256) void k_wc() {
    __shared__ float lds_s[256];
    int blk = blockIdx.x;
    int t = threadIdx.x;
    if (blk < WBLK) {
        int pos_local = t >> 3, j = t & 7;
        int idx = blk*32 + pos_local;
        int b = idx >> 11, p = idx & (NN-1);
        int gr = p >> 5, col = p & 31;
        const int dy[8] = {-1,-1,-1, 0,0, 1,1,1};
        const int dx[8] = {-1, 0, 1,-1,1,-1,0,1};
        int qr = gr + dy[j], qc = col + dx[j];
        bool ok = (qr >= 0) && (qr < HH) && (qc >= 0) && (qc < WW);
        int q = ok ? (qr*WW + qc) : p;
        const float4* ap = (const float4*)(g_as + (((size_t)b*NN + p) << 6));
        const float4* sp = (const float4*)(g_as + (((size_t)b*NN + q) << 6) + 32);
        float d = 0.f;
        #pragma unroll
        for (int k4 = 0; k4 < 8; ++k4) {
            float4 a = ap[k4], s = sp[k4];
            d = fmaf(a.x, s.x, d); d = fmaf(a.y, s.y, d);
            d = fmaf(a.z, s.z, d); d = fmaf(a.w, s.w, d);
        }
        float logit = ok ? d : NEGC;
        float m = logit;                       // max over the 8-lane neighbor group
        m = fmaxf(m, __shfl_xor(m, 1, 64));
        m = fmaxf(m, __shfl_xor(m, 2, 64));
        m = fmaxf(m, __shfl_xor(m, 4, 64));
        float e = expf(logit - m);
        float s8 = e;
        s8 += __shfl_xor(s8, 1, 64);
        s8 += __shfl_xor(s8, 2, 64);
        s8 += __shfl_xor(s8, 4, 64);
        g_w8[(size_t)idx*8 + j] = e / s8;
    } else {
        int b = blk - WBLK;
        float s = 0.f;
        #pragma unroll 8
        for (int tile = 0; tile < 32; ++tile) s += g_part[(b*32 + tile)*256 + t];
        lds_s[t] = s;                          // pair-dot for pair (t, t+1)
        __syncthreads();
        int c = t;
        float glo = (c > 0)      ? lds_s[c-1] : NEGC;
        float ghi = (c < CC - 1) ? lds_s[c]   : NEGC;
        float m = fmaxf(glo, ghi);
        float elo = expf(glo - m), ehi = expf(ghi - m);
        float inv = 1.0f / (elo + ehi);
        g_wlo[b*CC + c] = elo * inv;
        g_whi[b*CC + c] = ehi * inv;
    }
}

// ---------------- K3: stencil + channel blend + elu + mix (LDS-staged halo tile) ----
// grid: 2048 blocks = b(16) x strip(8 rows)(8) x cgroup(16 ch)(16); 4 waves = 4 ch each
// wq loaded straight from g_w8 into registers (no LDS wtab) -> 25.9 KB LDS, 6 blocks/CU
__global__ __launch_bounds__(256) void k_main(const float* __restrict__ x,
                                              const float* __restrict__ gama_p,
                                              float* __restrict__ out) {
    __shared__ float xt[18*10*36];
    int blk = blockIdx.x;
    int b = blk >> 7;
    int strip = (blk >> 4) & 7;
    int cg = blk & 15;
    int t = threadIdx.x;
    int r0 = strip << 3;
    int c0 = cg << 4;
    const float* xb = x + (size_t)b*CC*NN;

    int wave = __builtin_amdgcn_readfirstlane(t >> 6);
    int lane = t & 63;
    int lrow = lane >> 3;            // row within strip
    int lcq  = (lane & 7) << 2;      // column quad start

    // wq: this thread's 4 positions x 8 weights, straight from g_w8 (128B/lane, coalesced)
    float wq[4][8];
    {
        const float4* wp = (const float4*)(g_w8 +
            ((size_t)(b*NN + r0*WW + lrow*WW + lcq)) * 8);
        #pragma unroll
        for (int i = 0; i < 4; ++i) {
            float4 w0 = wp[2*i], w1 = wp[2*i+1];
            wq[i][0]=w0.x; wq[i][1]=w0.y; wq[i][2]=w0.z; wq[i][3]=w0.w;
            wq[i][4]=w1.x; wq[i][5]=w1.y; wq[i][6]=w1.z; wq[i][7]=w1.w;
        }
    }

    // stage x halo tile: 18*10 = 180 row-segments x 8 quads = 1440 float4
    for (int i = t; i < 1440; i += 256) {
        int seg = i >> 3, quad = i & 7;
        int ch_s = seg / 10, r_s = seg - ch_s*10;
        int gc = c0 - 1 + ch_s;  gc = (gc < 0) ? 0 : (gc > CC-1 ? CC-1 : gc);
        int gr = r0 - 1 + r_s;   gr = (gr < 0) ? 0 : (gr > HH-1 ? HH-1 : gr);
        float4 v = *(const float4*)(xb + (size_t)gc*NN + gr*WW + quad*4);
        *(float4*)(&xt[(ch_s*10 + r_s)*36 + quad*4]) = v;
    }
    __syncthreads();

    float gama = gama_p[0];
    int cw0 = wave*4;                // this wave's first channel (slot cw0+1)
    int pbase = r0*WW + lane*4;      // for the global store
    float* ob = out + (size_t)b*CC*NN;

    float pm1[4], o0[4];
    {
        float4 v = *(const float4*)(&xt[((cw0+0)*10 + (lrow+1))*36 + lcq]);   // slot c0-1+cw0
        pm1[0]=v.x; pm1[1]=v.y; pm1[2]=v.z; pm1[3]=v.w;
        float4 w = *(const float4*)(&xt[((cw0+1)*10 + (lrow+1))*36 + lcq]);   // own channel
        o0[0]=w.x; o0[1]=w.y; o0[2]=w.z; o0[3]=w.w;
    }
    #pragma unroll
    for (int cc = 0; cc < 4; ++cc) {
        int c = c0 + cw0 + cc;
        int slot = cw0 + 1 + cc;
        float4 v1 = *(const float4*)(&xt[((slot+1)*10 + (lrow+1))*36 + lcq]); // c+1 (clamped)
        float p1[4] = {v1.x, v1.y, v1.z, v1.w};
        float4 va4 = *(const float4*)(&xt[(slot*10 + lrow    )*36 + lcq]);    // row above (clamped)
        float aw[4] = {va4.x, va4.y, va4.z, va4.w};
        float4 vb4 = *(const float4*)(&xt[(slot*10 + lrow + 2)*36 + lcq]);    // row below (clamped)
        float bw[4] = {vb4.x, vb4.y, vb4.z, vb4.w};
        float al  = __shfl_up(aw[3], 1);
        float ar  = __shfl_down(aw[0], 1);
        float ol  = __shfl_up(o0[3], 1);
        float orr = __shfl_down(o0[0], 1);
        float bl  = __shfl_up(bw[3], 1);
        float br  = __shfl_down(bw[0], 1);
        float wlo_c = g_wlo[b*CC + c];
        float whi_c = g_whi[b*CC + c];
        float res[4];
        #pragma unroll
        for (int i = 0; i < 4; ++i) {
            float ul = (i == 0) ? al  : aw[i-1];
            float uu = aw[i];
            float ur = (i == 3) ? ar  : aw[i+1];
            float ll = (i == 0) ? ol  : o0[i-1];
            float rr = (i == 3) ? orr : o0[i+1];
            float dl = (i == 0) ? bl  : bw[i-1];
            float dd = bw[i];
            float dr = (i == 3) ? br  : bw[i+1];
            float hs = wq[i][0]*ul + wq[i][1]*uu + wq[i][2]*ur
                     + wq[i][3]*ll + wq[i][4]*rr
                     + wq[i][5]*dl + wq[i][6]*dd + wq[i][7]*dr;
            float hp = wlo_c*pm1[i] + whi_c*p1[i];
            float h  = hs + hp;
            float el = (h > 0.f) ? h : expm1f(h);
            res[i] = o0[i] + gama*(el - o0[i]);       // (1-g)x + g*h'
        }
        *(float4*)(ob + (size_t)c*NN + pbase) = make_float4(res[0], res[1], res[2], res[3]);
        #pragma unroll
        for (int i = 0; i < 4; ++i) { pm1[i] = o0[i]; o0[i] = p1[i]; }
    }
}

extern "C" void kernel_launch(void* const* d_in, const int* in_sizes, int n_in,
                              void* d_out, int out_size, void* d_ws, size_t ws_size,
                              hipStream_t stream) {
    const float* x    = (const float*)d_in[0];
    const float* wa   = (const float*)d_in[1];
    const float* ga   = (const float*)d_in[2];
    const float* ba   = (const float*)d_in[3];
    const float* ma   = (const float*)d_in[4];
    const float* va   = (const float*)d_in[5];
    const float* wsig = (const float*)d_in[6];
    const float* gs   = (const float*)d_in[7];
    const float* bs   = (const float*)d_in[8];
    const float* ms   = (const float*)d_in[9];
    const float* vs   = (const float*)d_in[10];
    const float* gama = (const float*)d_in[11];
    float* out = (float*)d_out;

    hipLaunchKernelGGL(k_gemm, dim3(512),      dim3(256), 0, stream,
                       x, wa, ga, va, ba, ma, wsig, gs, vs, bs, ms);
    hipLaunchKernelGGL(k_wc,   dim3(WBLK+BB),  dim3(256), 0, stream);
    hipLaunchKernelGGL(k_main, dim3(2048),     dim3(256), 0, stream, x, gama, out);
}